// Round 1
// baseline (6918.951 us; speedup 1.0000x reference)
//
#include <hip/hip_runtime.h>

#define S_   1024
#define ND   30
#define EPS_ 1e-6f

// sign of e_a * e_b in Cl(4,1): returns 1 if negative, 0 if positive.
__device__ __forceinline__ int cayley_neg(int a, int b) {
    int par = 0;
    for (int t = a >> 1; t; t >>= 1) par ^= __popc(t & b) & 1;
    par ^= ((a & b) >> 4) & 1;   // metric: generator 4 has e4*e4 = -1
    return par & 1;
}

__launch_bounds__(512, 1)
__global__ void versor_kernel(const float* __restrict__ x,
                              const float* __restrict__ W_in,
                              const float* __restrict__ b_in,
                              const float* __restrict__ w_h,
                              const float* __restrict__ w_x,
                              const float* __restrict__ W_out,
                              const float* __restrict__ b_out,
                              float* __restrict__ out) {
    const int b    = blockIdx.x;
    const int tid  = threadIdx.x;
    const int o    = tid >> 5;   // 0..15  (output channel / j-group)
    const int lane = tid & 31;   // n in T-phase, k in h-phase, p in out-phase

    __shared__ __align__(16) float gmi[32][36];  // [m][ich], padded rows (144B, 16B-aligned)
    __shared__ float xt[32];
    __shared__ float red[16 * 32];

    // ---- per-thread constant registers (loaded once) ----
    float w_reg[32];                     // W[(o,lane)][ich]: w_h then w_x
    #pragma unroll
    for (int ich = 0; ich < 16; ++ich) {
        w_reg[ich]      = w_h[(o * 16 + ich) * 32 + lane];
        w_reg[ich + 16] = w_x[(o * 16 + ich) * 32 + lane];
    }
    float win_reg[ND];                   // column tid of W_in
    #pragma unroll
    for (int p = 0; p < ND; ++p) win_reg[p] = W_in[p * 512 + tid];
    const float bin_reg = b_in[tid];

    const int pc = (lane < ND) ? lane : 0;
    float wout_reg[32];                  // W_out[(o*32+jj)][pc]
    #pragma unroll
    for (int jj = 0; jj < 32; ++jj) wout_reg[jj] = W_out[(o * 32 + jj) * ND + pc];
    const float bout_reg = (tid < ND) ? b_out[tid] : 0.0f;

    unsigned sbits = 0;                  // bit m: sign of s(m, n=lane)
    for (int m = 0; m < 32; ++m) sbits |= (unsigned)cayley_neg(m, lane) << m;

    float h_reg = 0.0f;
    gmi[lane][o] = 0.0f;                 // zero the h-columns (ich = o < 16)

    const float* xrow = x   + (size_t)b * S_ * ND;
    float*       orow = out + (size_t)b * S_ * ND;

    for (int s = 0; s < S_; ++s) {
        if (tid < ND) xt[tid] = xrow[s * ND + tid];
        __syncthreads();                           // xt visible (also gmi init on s=0)

        // ---- x_emb: xe[tid] = b_in + x_t . W_in[:,tid]; write G xe-columns ----
        float acc = bin_reg;
        #pragma unroll
        for (int p = 0; p < ND; ++p) acc += xt[p] * win_reg[p];
        gmi[lane][16 + o] = acc;
        __syncthreads();                           // G complete (h cols from prev step)

        // ---- T-phase: Treg[m] = G[m,:] . w_reg ; apply sign s(m, lane) ----
        float a[32];
        #pragma unroll
        for (int m = 0; m < 32; ++m) {
            float t0 = 0.f, t1 = 0.f, t2 = 0.f, t3 = 0.f;
            const float* gp = &gmi[m][0];
            #pragma unroll
            for (int q = 0; q < 8; ++q) {
                float4 gv = *(const float4*)(gp + q * 4);   // uniform address -> broadcast
                t0 += gv.x * w_reg[q * 4 + 0];
                t1 += gv.y * w_reg[q * 4 + 1];
                t2 += gv.z * w_reg[q * 4 + 2];
                t3 += gv.w * w_reg[q * 4 + 3];
            }
            float t = (t0 + t1) + (t2 + t3);
            a[m] = __uint_as_float(__float_as_uint(t) ^ (((sbits >> m) & 1u) << 31));
        }

        // ---- butterfly: delta[o][k] = sum_n s(k^n,n)*T[k^n][o,n] lands at lane k ----
        #pragma unroll
        for (int m = 0; m < 32; m += 2)  a[m] += __shfl_xor(a[m ^ 1], 1, 32);
        #pragma unroll
        for (int m = 0; m < 32; m += 4)  a[m] += __shfl_xor(a[m ^ 2], 2, 32);
        #pragma unroll
        for (int m = 0; m < 32; m += 8)  a[m] += __shfl_xor(a[m ^ 4], 4, 32);
        #pragma unroll
        for (int m = 0; m < 32; m += 16) a[m] += __shfl_xor(a[m ^ 8], 8, 32);
        a[0] += __shfl_xor(a[16], 16, 32);

        // ---- residual + per-channel L2 normalize (32-lane group = one channel) ----
        float hc = h_reg + a[0];
        float ss = hc * hc;
        #pragma unroll
        for (int mask = 1; mask < 32; mask <<= 1) ss += __shfl_xor(ss, mask, 32);
        h_reg = hc / (sqrtf(ss) + EPS_);

        __syncthreads();                           // all G reads of this step done
        gmi[lane][o] = h_reg;                      // h for next step + W_out phase
        __syncthreads();

        // ---- output: out[p] = x_t[p] + h_new . W_out[:,p] + b_out[p] ----
        float oacc = 0.0f;
        #pragma unroll
        for (int jj = 0; jj < 32; ++jj) oacc += gmi[jj][o] * wout_reg[jj];
        red[o * 32 + lane] = oacc;
        __syncthreads();
        if (tid < ND) {
            float ov = xt[tid] + bout_reg;
            #pragma unroll
            for (int jg = 0; jg < 16; ++jg) ov += red[jg * 32 + tid];
            orow[s * ND + tid] = ov;
        }
        __syncthreads();                           // red/xt reuse next step
    }
}

extern "C" void kernel_launch(void* const* d_in, const int* in_sizes, int n_in,
                              void* d_out, int out_size, void* d_ws, size_t ws_size,
                              hipStream_t stream) {
    const float* x     = (const float*)d_in[0];
    const float* W_in  = (const float*)d_in[1];
    const float* b_in  = (const float*)d_in[2];
    const float* w_h   = (const float*)d_in[3];
    const float* w_x   = (const float*)d_in[4];
    const float* W_out = (const float*)d_in[5];
    const float* b_out = (const float*)d_in[6];
    float* outp = (float*)d_out;

    versor_kernel<<<256, 512, 0, stream>>>(x, W_in, b_in, w_h, w_x, W_out, b_out, outp);
}